// Round 4
// baseline (1211.064 us; speedup 1.0000x reference)
//
#include <hip/hip_runtime.h>

// MultiLoraLinear: y = x@W^T + bias + (x@A^T)@Bw^T (per-segment adapter, scale=1)
// M=16384 (8x2048), K=4096, N=4096, r=16.
// bf16-cast + MFMA NT-GEMM, 256x256 8-phase template (T1 XCD swizzle + T2 LDS
// XOR swizzle + T3/T4 counted-vmcnt + T5 setprio) with snake fragment reuse
// (24 ds_read_b128/K-tile) AND one-phase ds_read READ-AHEAD: each phase's
// fragment reads are issued in the previous phase's post-barrier window, so
// the LDS pipe overlaps the MFMA pipe instead of serializing against it
// (round-3 measured: serialized reads held MfmaUtil at 36.5%).
// Stage/VMCNT/barrier skeleton is unchanged from the verified round-3 kernel.
// LoRA folded in as one extra K=32 tile (u = x@A^T; Bw padded to 32 cols).

typedef __attribute__((ext_vector_type(8))) short short8;
typedef __attribute__((ext_vector_type(4))) float f32x4;
typedef __attribute__((ext_vector_type(4))) unsigned short u16x4;
typedef unsigned short u16;

typedef __attribute__((address_space(1))) void as1_void;
typedef __attribute__((address_space(3))) void as3_void;

#define M_DIM 16384
#define N_DIM 4096
#define K_DIM 4096
#define K2 8192  // K_DIM * sizeof(bf16) bytes per row
#define BM 256
#define BN 256
#define BK 64

__device__ __forceinline__ u16 f2bf(float f) {
  union { float f; unsigned u; } v; v.f = f;
  unsigned r = (v.u + 0x7FFFu + ((v.u >> 16) & 1u)) >> 16;  // RNE
  return (u16)r;
}
__device__ __forceinline__ float bf2f(u16 u) {
  union { unsigned u; float f; } v; v.u = ((unsigned)u) << 16;
  return v.f;
}
__device__ __forceinline__ void gload16(const void* g, void* lds) {
  // async global->LDS, 16B/lane; LDS dest = wave-uniform base + lane*16
  __builtin_amdgcn_global_load_lds((as1_void*)g, (as3_void*)lds, 16, 0, 0);
}
__device__ __forceinline__ int seg_of_batch(const int* starts, int b) {
  int seg = -1;
#pragma unroll
  for (int i = 0; i < 4; ++i) seg += (starts[i] <= b) ? 1 : 0;
  return seg;  // 0 = no LoRA; adapter = clamp(seg-1, 0, 2)
}

#define VMCNT(n) asm volatile("s_waitcnt vmcnt(" #n ")" ::: "memory")
#define BAR() __builtin_amdgcn_s_barrier()

// ---------------- prep: fp32 -> bf16 casts + padded Bw ----------------
__global__ __launch_bounds__(256) void prep_kernel(
    const float* __restrict__ x, const float* __restrict__ wgt,
    const float* __restrict__ lA, const float* __restrict__ lB,
    u16* __restrict__ xbf, u16* __restrict__ wbf,
    u16* __restrict__ abf, u16* __restrict__ bw) {
  const long long NX4 = 16777216LL;  // 67108864/4
  const long long NW4 = 4194304LL;   // 16777216/4
  const long long NA4 = 49152LL;     // 196608/4
  const long long NB  = 12288LL;     // 3*4096 (a,n) rows of lora_B
  const long long total = NX4 + NW4 + NA4 + NB;
  const f32x4* x4 = (const f32x4*)x;
  const f32x4* w4 = (const f32x4*)wgt;
  const f32x4* a4 = (const f32x4*)lA;
  u16x4* xo = (u16x4*)xbf;
  u16x4* wo = (u16x4*)wbf;
  u16x4* ao = (u16x4*)abf;
  for (long long i = (long long)blockIdx.x * blockDim.x + threadIdx.x; i < total;
       i += (long long)gridDim.x * blockDim.x) {
    if (i < NX4) {
      f32x4 v = x4[i];
      u16x4 o = {f2bf(v.x), f2bf(v.y), f2bf(v.z), f2bf(v.w)};
      xo[i] = o;
    } else if (i < NX4 + NW4) {
      long long j = i - NX4;
      f32x4 v = w4[j];
      u16x4 o = {f2bf(v.x), f2bf(v.y), f2bf(v.z), f2bf(v.w)};
      wo[j] = o;
    } else if (i < NX4 + NW4 + NA4) {
      long long j = i - NX4 - NW4;
      f32x4 v = a4[j];
      u16x4 o = {f2bf(v.x), f2bf(v.y), f2bf(v.z), f2bf(v.w)};
      ao[j] = o;
    } else {
      long long p = i - NX4 - NW4 - NA4;  // flat (a*4096+n)
      const float* src = lB + p * 16;
      u16* dst = bw + p * 32;
#pragma unroll
      for (int j = 0; j < 16; ++j) dst[j] = f2bf(src[j]);
#pragma unroll
      for (int j = 16; j < 32; ++j) dst[j] = 0;
    }
  }
}

// ---------------- u = x @ A^T  -> bf16 [M][32], zero-padded ----------------
__global__ __launch_bounds__(256) void ucompute_kernel(
    const u16* __restrict__ xbf, const u16* __restrict__ abf,
    const int* __restrict__ starts, u16* __restrict__ u) {
  const int l = threadIdx.x & 63;
  const int w = threadIdx.x >> 6;
  const int mbase = blockIdx.x * 16 + w * 4;
  const int b = mbase >> 11;  // /2048
  const int seg = seg_of_batch(starts, b);
  const int use = seg > 0;
  int ad = seg - 1; ad = ad < 0 ? 0 : (ad > 2 ? 2 : ad);

  float acc[4][16];
#pragma unroll
  for (int row = 0; row < 4; ++row)
#pragma unroll
    for (int r = 0; r < 16; ++r) acc[row][r] = 0.f;

  if (use) {
    const u16* xr = xbf + (size_t)mbase * K_DIM + l * 8;
    const u16* ar = abf + (size_t)ad * (16 * K_DIM) + l * 8;
    for (int pass = 0; pass < 8; ++pass) {
      const int off = pass * 512;
      float xv[4][8];
#pragma unroll
      for (int row = 0; row < 4; ++row) {
        short8 xs = *(const short8*)(xr + (size_t)row * K_DIM + off);
#pragma unroll
        for (int j = 0; j < 8; ++j) xv[row][j] = bf2f((u16)xs[j]);
      }
#pragma unroll
      for (int r = 0; r < 16; ++r) {
        short8 av = *(const short8*)(ar + (size_t)r * K_DIM + off);
#pragma unroll
        for (int j = 0; j < 8; ++j) {
          float a = bf2f((u16)av[j]);
#pragma unroll
          for (int row = 0; row < 4; ++row) acc[row][r] += xv[row][j] * a;
        }
      }
    }
  }
#pragma unroll
  for (int row = 0; row < 4; ++row) {
    float myval = 0.f;
#pragma unroll
    for (int r = 0; r < 16; ++r) {
      float v = acc[row][r];
      v += __shfl_xor(v, 32);
      v += __shfl_xor(v, 16);
      v += __shfl_xor(v, 8);
      v += __shfl_xor(v, 4);
      v += __shfl_xor(v, 2);
      v += __shfl_xor(v, 1);
      if (l == r) myval = v;  // lane r keeps u[m][r]
    }
    if (l < 32) u[(size_t)(mbase + row) * 32 + l] = (l < 16) ? f2bf(myval) : (u16)0;
  }
}

// ---------------- main NT-GEMM, 256x256 tile, 8-phase + read-ahead ----------
// 512 threads = 8 waves (2 M-waves x 4 N-waves); each wave owns 128x64 output.
// K-tile = 64. LDS: 2 x (A 32KB + B 32KB) = 128KB double buffer.
// Snake consumption per K-tile: (ih,jh) = (0,0),(0,1),(1,1),(1,0).
// Read-ahead: fragment ds_reads for phase p+1 issue after barrier1(p), before
// the MFMA cluster of phase p -> LDS pipe overlaps MFMA pipe. Read slots:
//   P8-post: A0+B0(buf0,next-even-tile) [12]   P1-post: B1(buf0) [4]
//   P2-post: A1(buf0) [8]                      P3-post: - [0]
//   P4-post: A0+B0(buf1,odd-tile) [12]         P5-post: B1(buf1) [4]
//   P6-post: A1(buf1) [8]                      P7-post: - [0]
// All read slots sit after the P4/P8 VMCNT(6)+barrier that syncs their buffer
// (verified region-by-region); every region's readers complete >=1 barrier
// before its re-stage (stage schedule unchanged from round-3, harness-passed).
// Fragments: aF0r/aF1r alternate (no conflict); bF0A/bF0B parity-double-
// buffered (B0 consumed at both snake ends, P1 & P4); bF1r single.
// Staging/waits: one 16KB region per phase pre-slot; VMCNT(6) at P4/P8 only.
// T2 swizzle: physical 16B slot = logical slot ^ (row&7), applied on the
// gload16 *global source* (LDS dest linear, rule #21) and on ds_read.

#define STAGE_A(buf, ih, kt) do { \
  gload16(aSrc + (size_t)((ih)*64) * K2 + (size_t)(kt)*128, \
          &As[buf][((ih)*64) * BK] + w * 512); \
  gload16(aSrc + (size_t)((ih)*64 + 128) * K2 + (size_t)(kt)*128, \
          &As[buf][((ih)*64 + 128) * BK] + w * 512); \
} while (0)
#define STAGE_B(buf, jh, kt) do { \
  gload16(bSrc + (size_t)((jh)*32) * K2 + (size_t)(kt)*128, \
          &Bs[buf][((jh)*32 + (w >> 2)*64) * BK] + (w & 3) * 512); \
  gload16(bSrc + (size_t)((jh)*32 + 128) * K2 + (size_t)(kt)*128, \
          &Bs[buf][((jh)*32 + (w >> 2)*64 + 128) * BK] + (w & 3) * 512); \
} while (0)

#define READ_A(dst, buf, ih) do { \
  _Pragma("unroll") \
  for (int i2 = 0; i2 < 4; ++i2) { \
    const u16* ar = &As[buf][(wr*128 + (ih)*64 + i2*16 + fm) * BK]; \
    dst[i2][0] = *(const short8*)(ar + c0); \
    dst[i2][1] = *(const short8*)(ar + c1); \
  } \
} while (0)
#define READ_B(dst, buf, jh) do { \
  _Pragma("unroll") \
  for (int j2 = 0; j2 < 2; ++j2) { \
    const u16* br = &Bs[buf][(wc*64 + (jh)*32 + j2*16 + fm) * BK]; \
    dst[j2][0] = *(const short8*)(br + c0); \
    dst[j2][1] = *(const short8*)(br + c1); \
  } \
} while (0)

#define MFMA16(ih, jh, A, B) do { \
  __builtin_amdgcn_s_setprio(1); \
  _Pragma("unroll") \
  for (int i2 = 0; i2 < 4; ++i2) \
  _Pragma("unroll") \
  for (int j2 = 0; j2 < 2; ++j2) { \
    acc[(ih)*4 + i2][(jh)*2 + j2] = __builtin_amdgcn_mfma_f32_16x16x32_bf16( \
        A[i2][0], B[j2][0], acc[(ih)*4 + i2][(jh)*2 + j2], 0, 0, 0); \
    acc[(ih)*4 + i2][(jh)*2 + j2] = __builtin_amdgcn_mfma_f32_16x16x32_bf16( \
        A[i2][1], B[j2][1], acc[(ih)*4 + i2][(jh)*2 + j2], 0, 0, 0); \
  } \
  __builtin_amdgcn_s_setprio(0); \
} while (0)

__global__ __launch_bounds__(512, 2) void gemm8_kernel(
    const u16* __restrict__ xbf, const u16* __restrict__ wbf,
    const float* __restrict__ bias, const u16* __restrict__ ubuf,
    const u16* __restrict__ bwpad, const int* __restrict__ starts,
    float* __restrict__ out) {
  __shared__ u16 As[2][BM * BK];  // 64 KB
  __shared__ u16 Bs[2][BN * BK];  // 64 KB

  const int tid = threadIdx.x;
  const int l = tid & 63;
  const int w = tid >> 6;

  // T1: bijective XCD swizzle (1024 blocks, 1024 % 8 == 0)
  const int bid = blockIdx.x;
  const int nb = (bid & 7) * 128 + (bid >> 3);
  const int m0 = (nb >> 4) << 8;  // 64 M-tiles
  const int n0 = (nb & 15) << 8;  // 16 N-tiles

  const int b = m0 >> 11;  // block fully inside one batch sample (2048 rows)
  const int seg = seg_of_batch(starts, b);
  int ad = seg - 1; ad = ad < 0 ? 0 : (ad > 2 ? 2 : ad);
  // (no-LoRA blocks: u rows are zero, so the LoRA tile contributes nothing)

  // ---- staging constants: wave w covers 8 consecutive rows per gload16 ----
  const int lrow = l >> 3;                  // row within 8-row chunk
  const int swzslot = (l & 7) ^ lrow;       // pre-swizzled global 16B slot
  const char* aSrc = (const char*)xbf +
      (size_t)(m0 + 8 * w + lrow) * K2 + swzslot * 16;
  const char* bSrc = (const char*)wbf +
      (size_t)(n0 + (w >> 2) * 64 + (w & 3) * 8 + lrow) * K2 + swzslot * 16;

  // ---- fragment-read constants ----
  const int fm = l & 15;
  const int q = l >> 4;
  const int wr = w >> 2;  // 0..1
  const int wc = w & 3;   // 0..3
  const int c0 = ((q ^ (fm & 7)) * 8);        // u16 offset, k-step 0 (swizzled)
  const int c1 = (((q + 4) ^ (fm & 7)) * 8);  // u16 offset, k-step 1

  f32x4 acc[8][4];
  const f32x4 z4 = {0.f, 0.f, 0.f, 0.f};
#pragma unroll
  for (int i = 0; i < 8; ++i)
#pragma unroll
    for (int j = 0; j < 4; ++j) acc[i][j] = z4;

  // persistent register fragments
  short8 aF0r[4][2];  // A ih=0 half (reloaded P8-post / P4-post)
  short8 aF1r[4][2];  // A ih=1 half (reloaded P2-post / P6-post)
  short8 bF0A[2][2];  // B jh=0, odd-tile parity (loaded P4-post)
  short8 bF0B[2][2];  // B jh=0, even-tile parity (loaded P8-post/prologue)
  short8 bF1r[2][2];  // B jh=1 (reloaded P1-post / P5-post)

  // ---- prologue: all 4 regions of tile0 (buf0) + 3 regions of tile1 (buf1);
  // VMCNT(6) completes the oldest 8 loads = all of tile0; then the initial
  // read-ahead (A0+B0 of tile0) issues after the barrier.
  STAGE_A(0, 0, 0); STAGE_B(0, 0, 0); STAGE_B(0, 1, 0); STAGE_A(0, 1, 0);
  STAGE_A(1, 0, 1); STAGE_B(1, 1, 1); STAGE_A(1, 1, 1);
  VMCNT(6);
  BAR();
  READ_A(aF0r, 0, 0);
  READ_B(bF0B, 0, 0);

  // ---- main loop: 32 iterations x 2 K-tiles (K = 64 tiles) ----
  // Stage slots (pre-barrier1, unchanged from round-3):
  //  P1: B0(b1,t1)  P2: A0(b0,t2)  P3: B1(b0,t2)  P4: A1(b0,t2)
  //  P5: B0(b0,t2)  P6: A0(b1,t3)  P7: B1(b1,t3)  P8: A1(b1,t3)
  for (int s = 0; s < 32; ++s) {
    const int t1 = 2 * s + 1;
    const int t2 = 2 * s + 2;
    const int t3 = 2 * s + 3;
    const bool more = (s < 31);

    // P1: consume (0,0) with A0,B0(even parity)
    STAGE_B(1, 0, t1);
    BAR();
    READ_B(bF1r, 0, 1);
    MFMA16(0, 0, aF0r, bF0B);
    BAR();

    // P2: consume (0,1)
    if (more) STAGE_A(0, 0, t2);
    BAR();
    READ_A(aF1r, 0, 1);
    MFMA16(0, 1, aF0r, bF1r);
    BAR();

    // P3: consume (1,1) — no reads (all operands resident)
    if (more) STAGE_B(0, 1, t2);
    BAR();
    MFMA16(1, 1, aF1r, bF1r);
    BAR();

    // P4: consume (1,0); sync point; read-ahead tile t1 (buf1) A0+B0
    if (more) STAGE_A(0, 1, t2);
    if (more) { VMCNT(6); } else { VMCNT(0); }
    BAR();
    READ_A(aF0r, 1, 0);
    READ_B(bF0A, 1, 0);
    MFMA16(1, 0, aF1r, bF0B);
    BAR();

    // P5: consume (0,0) of t1 with A0,B0(odd parity)
    if (more) STAGE_B(0, 0, t2);
    BAR();
    READ_B(bF1r, 1, 1);
    MFMA16(0, 0, aF0r, bF0A);
    BAR();

    // P6: consume (0,1)
    if (more) STAGE_A(1, 0, t3);
    BAR();
    READ_A(aF1r, 1, 1);
    MFMA16(0, 1, aF0r, bF1r);
    BAR();

    // P7: consume (1,1) — no reads
    if (more) STAGE_B(1, 1, t3);
    BAR();
    MFMA16(1, 1, aF1r, bF1r);
    BAR();

    // P8: consume (1,0); sync point; read-ahead tile t2 (buf0) A0+B0
    if (more) STAGE_A(1, 1, t3);
    if (more) { VMCNT(6); } else { VMCNT(0); }
    BAR();
    if (more) {
      READ_A(aF0r, 0, 0);
      READ_B(bF0B, 0, 0);
    }
    MFMA16(1, 0, aF1r, bF0A);
    BAR();
  }

  // ---- LoRA K=32 tile: A = u[M][32], B = bwpad[ad][N][32]; into buf0 flat ----
  {
    u16* la = &As[0][0];  // [256][32] packed, 16KB
    u16* lb = &Bs[0][0];
    const int ls = l & 3;  // 16B slot within 64B row
    const int lr = l >> 2; // row within 16-row chunk
    const char* uSrc = (const char*)ubuf +
        (size_t)(m0 + 16 * w + lr) * 64 + ls * 16;
    const char* vSrc = (const char*)bwpad +
        ((size_t)ad * N_DIM + n0 + 16 * w + lr) * 64 + ls * 16;
    gload16(uSrc, la + (16 * w) * 32);
    gload16(uSrc + (size_t)128 * 64, la + (128 + 16 * w) * 32);
    gload16(vSrc, lb + (16 * w) * 32);
    gload16(vSrc + (size_t)128 * 64, lb + (128 + 16 * w) * 32);
    VMCNT(0);
    BAR();
    short8 aF[8], bF[4];
#pragma unroll
    for (int i = 0; i < 8; ++i)
      aF[i] = *(const short8*)(la + (wr * 128 + i * 16 + fm) * 32 + q * 8);
#pragma unroll
    for (int j = 0; j < 4; ++j)
      bF[j] = *(const short8*)(lb + (wc * 64 + j * 16 + fm) * 32 + q * 8);
#pragma unroll
    for (int i = 0; i < 8; ++i)
#pragma unroll
      for (int j = 0; j < 4; ++j)
        acc[i][j] = __builtin_amdgcn_mfma_f32_16x16x32_bf16(aF[i], bF[j],
                                                            acc[i][j], 0, 0, 0);
  }

  // ---- epilogue: C/D layout col=l&15, row=(l>>4)*4+reg ----
  float bv[4];
#pragma unroll
  for (int j = 0; j < 4; ++j) bv[j] = bias[n0 + wc * 64 + j * 16 + fm];
#pragma unroll
  for (int i = 0; i < 8; ++i) {
#pragma unroll
    for (int ii = 0; ii < 4; ++ii) {
      const int m = m0 + wr * 128 + i * 16 + q * 4 + ii;
      float* orow = out + (size_t)m * N_DIM + n0 + wc * 64 + fm;
#pragma unroll
      for (int j = 0; j < 4; ++j) orow[j * 16] = acc[i][j][ii] + bv[j];
    }
  }
}

// ---------------- fp32 fallback (only if ws_size < fast-path need) ----------------
__global__ __launch_bounds__(256) void u_f32_kernel(
    const float* __restrict__ x, const float* __restrict__ lA,
    const int* __restrict__ starts, float* __restrict__ u) {
  const int l = threadIdx.x & 63;
  const int w = threadIdx.x >> 6;
  const int m = blockIdx.x * 4 + w;
  const int b = m >> 11;
  const int seg = seg_of_batch(starts, b);
  const int use = seg > 0;
  int ad = seg - 1; ad = ad < 0 ? 0 : (ad > 2 ? 2 : ad);
  float acc[16];
#pragma unroll
  for (int r = 0; r < 16; ++r) acc[r] = 0.f;
  if (use) {
    const float* xr = x + (size_t)m * K_DIM + l * 4;
    const float* ar = lA + (size_t)ad * (16 * K_DIM) + l * 4;
    for (int pass = 0; pass < 16; ++pass) {
      const int off = pass * 256;
      f32x4 xv = *(const f32x4*)(xr + off);
#pragma unroll
      for (int r = 0; r < 16; ++r) {
        f32x4 av = *(const f32x4*)(ar + (size_t)r * K_DIM + off);
        acc[r] += xv.x * av.x + xv.y * av.y + xv.z * av.z + xv.w * av.w;
      }
    }
  }
  float myval = 0.f;
#pragma unroll
  for (int r = 0; r < 16; ++r) {
    float v = acc[r];
    v += __shfl_xor(v, 32);
    v += __shfl_xor(v, 16);
    v += __shfl_xor(v, 8);
    v += __shfl_xor(v, 4);
    v += __shfl_xor(v, 2);
    v += __shfl_xor(v, 1);
    if (l == r) myval = v;
  }
  if (l < 16) u[(size_t)m * 16 + l] = myval;
}

__global__ __launch_bounds__(256) void gemm_f32_fallback(
    const float* __restrict__ x, const float* __restrict__ wgt,
    const float* __restrict__ bias, const float* __restrict__ lB,
    const float* __restrict__ u, const int* __restrict__ starts,
    float* __restrict__ out) {
  __shared__ float xs[4096];
  const int m = blockIdx.y;
  const int n0 = blockIdx.x * 256;
  const int t = threadIdx.x;
  const f32x4* xr4 = (const f32x4*)(x + (size_t)m * K_DIM);
  f32x4* xs4 = (f32x4*)xs;
  for (int i = t; i < 1024; i += 256) xs4[i] = xr4[i];
  __syncthreads();
  const int b = m >> 11;
  const int seg = seg_of_batch(starts, b);
  const int use = seg > 0;
  int ad = seg - 1; ad = ad < 0 ? 0 : (ad > 2 ? 2 : ad);
  const int n = n0 + t;
  const f32x4* wr = (const f32x4*)(wgt + (size_t)n * K_DIM);
  float acc = 0.f;
  for (int kk = 0; kk < 1024; ++kk) {
    f32x4 wv = wr[kk];
    f32x4 xv = xs4[kk];
    acc += xv.x * wv.x + xv.y * wv.y + xv.z * wv.z + xv.w * wv.w;
  }
  acc += bias[n];
  if (use) {
    const float* Bn = lB + ((size_t)ad * N_DIM + n) * 16;
    const float* um = u + (size_t)m * 16;
    float lo = 0.f;
#pragma unroll
    for (int r = 0; r < 16; ++r) lo += um[r] * Bn[r];
    acc += lo;
  }
  out[(size_t)m * N_DIM + n] = acc;
}

extern "C" void kernel_launch(void* const* d_in, const int* in_sizes, int n_in,
                              void* d_out, int out_size, void* d_ws, size_t ws_size,
                              hipStream_t stream) {
  const float* x    = (const float*)d_in[0];
  const float* wgt  = (const float*)d_in[1];
  const float* bias = (const float*)d_in[2];
  const float* lA   = (const float*)d_in[3];
  const float* lB   = (const float*)d_in[4];
  const int* starts = (const int*)d_in[5];
  float* out = (float*)d_out;

  const size_t XBF_OFF = 0;                      // 134217728 B
  const size_t WBF_OFF = 134217728;              //  33554432 B
  const size_t ABF_OFF = 167772160;              //    393216 B
  const size_t BW_OFF  = 168165376;              //    786432 B
  const size_t U_OFF   = 168951808;              //   1048576 B
  const size_t WS_NEEDED = 170000384;

  if (ws_size >= WS_NEEDED) {
    u16* xbf = (u16*)((char*)d_ws + XBF_OFF);
    u16* wbf = (u16*)((char*)d_ws + WBF_OFF);
    u16* abf = (u16*)((char*)d_ws + ABF_OFF);
    u16* bw  = (u16*)((char*)d_ws + BW_OFF);
    u16* u   = (u16*)((char*)d_ws + U_OFF);
    prep_kernel<<<8192, 256, 0, stream>>>(x, wgt, lA, lB, xbf, wbf, abf, bw);
    ucompute_kernel<<<1024, 256, 0, stream>>>(xbf, abf, starts, u);
    gemm8_kernel<<<1024, 512, 0, stream>>>(xbf, wbf, bias, u, bw, starts, out);
  } else {
    // fp32 fallback: needs only 1 MB of ws for u
    float* uf = (float*)d_ws;
    u_f32_kernel<<<4096, 256, 0, stream>>>(x, lA, starts, uf);
    gemm_f32_fallback<<<dim3(16, 16384), 256, 0, stream>>>(x, wgt, bias, lB, uf, starts, out);
  }
}

// Round 5
// 1098.433 us; speedup vs baseline: 1.1025x; 1.1025x over previous
//
#include <hip/hip_runtime.h>

// MultiLoraLinear: y = x@W^T + bias + (x@A^T)@Bw^T (per-segment adapter, scale=1)
// M=16384 (8x2048), K=4096, N=4096, r=16.
// bf16-cast + MFMA NT-GEMM, 256x256 tile, 8 waves, BK=64, dbuf LDS (128KB).
// Round-5 schedule: single barrier per window; window = {BAR; MFMA(p);
// ds_reads(p+1); stage; counted VMCNT}. The lgkm wait for a phase's operands
// sits one full window after issue -> ~free; LDS pipe overlaps matrix pipe
// across waves (round-3 measured serial-sum: MfmaUtil 36.5%).
// All publication (vmcnt+barrier) and write-hazard (read-complete < re-stage)
// edges re-derived for the single-barrier schedule -- see window comments.
// T1 XCD swizzle + T2 LDS XOR swizzle + T4 counted vmcnt + T5 setprio kept.
// LoRA folded in as one extra K=32 tile (u = x@A^T; Bw padded to 32 cols).

typedef __attribute__((ext_vector_type(8))) short short8;
typedef __attribute__((ext_vector_type(4))) float f32x4;
typedef __attribute__((ext_vector_type(4))) unsigned short u16x4;
typedef unsigned short u16;

typedef __attribute__((address_space(1))) void as1_void;
typedef __attribute__((address_space(3))) void as3_void;

#define M_DIM 16384
#define N_DIM 4096
#define K_DIM 4096
#define K2 8192  // K_DIM * sizeof(bf16) bytes per row
#define BM 256
#define BN 256
#define BK 64

__device__ __forceinline__ u16 f2bf(float f) {
  union { float f; unsigned u; } v; v.f = f;
  unsigned r = (v.u + 0x7FFFu + ((v.u >> 16) & 1u)) >> 16;  // RNE
  return (u16)r;
}
__device__ __forceinline__ float bf2f(u16 u) {
  union { unsigned u; float f; } v; v.u = ((unsigned)u) << 16;
  return v.f;
}
__device__ __forceinline__ void gload16(const void* g, void* lds) {
  // async global->LDS, 16B/lane; LDS dest = wave-uniform base + lane*16
  __builtin_amdgcn_global_load_lds((as1_void*)g, (as3_void*)lds, 16, 0, 0);
}
__device__ __forceinline__ int seg_of_batch(const int* starts, int b) {
  int seg = -1;
#pragma unroll
  for (int i = 0; i < 4; ++i) seg += (starts[i] <= b) ? 1 : 0;
  return seg;  // 0 = no LoRA; adapter = clamp(seg-1, 0, 2)
}

#define VMCNT(n) asm volatile("s_waitcnt vmcnt(" #n ")" ::: "memory")
#define BAR() __builtin_amdgcn_s_barrier()

// ---------------- prep: fp32 -> bf16 casts + padded Bw ----------------
__global__ __launch_bounds__(256) void prep_kernel(
    const float* __restrict__ x, const float* __restrict__ wgt,
    const float* __restrict__ lA, const float* __restrict__ lB,
    u16* __restrict__ xbf, u16* __restrict__ wbf,
    u16* __restrict__ abf, u16* __restrict__ bw) {
  const long long NX4 = 16777216LL;  // 67108864/4
  const long long NW4 = 4194304LL;   // 16777216/4
  const long long NA4 = 49152LL;     // 196608/4
  const long long NB  = 12288LL;     // 3*4096 (a,n) rows of lora_B
  const long long total = NX4 + NW4 + NA4 + NB;
  const f32x4* x4 = (const f32x4*)x;
  const f32x4* w4 = (const f32x4*)wgt;
  const f32x4* a4 = (const f32x4*)lA;
  u16x4* xo = (u16x4*)xbf;
  u16x4* wo = (u16x4*)wbf;
  u16x4* ao = (u16x4*)abf;
  for (long long i = (long long)blockIdx.x * blockDim.x + threadIdx.x; i < total;
       i += (long long)gridDim.x * blockDim.x) {
    if (i < NX4) {
      f32x4 v = x4[i];
      u16x4 o = {f2bf(v.x), f2bf(v.y), f2bf(v.z), f2bf(v.w)};
      xo[i] = o;
    } else if (i < NX4 + NW4) {
      long long j = i - NX4;
      f32x4 v = w4[j];
      u16x4 o = {f2bf(v.x), f2bf(v.y), f2bf(v.z), f2bf(v.w)};
      wo[j] = o;
    } else if (i < NX4 + NW4 + NA4) {
      long long j = i - NX4 - NW4;
      f32x4 v = a4[j];
      u16x4 o = {f2bf(v.x), f2bf(v.y), f2bf(v.z), f2bf(v.w)};
      ao[j] = o;
    } else {
      long long p = i - NX4 - NW4 - NA4;  // flat (a*4096+n)
      const float* src = lB + p * 16;
      u16* dst = bw + p * 32;
#pragma unroll
      for (int j = 0; j < 16; ++j) dst[j] = f2bf(src[j]);
#pragma unroll
      for (int j = 16; j < 32; ++j) dst[j] = 0;
    }
  }
}

// ---------------- u = x @ A^T  -> bf16 [M][32], zero-padded ----------------
__global__ __launch_bounds__(256) void ucompute_kernel(
    const u16* __restrict__ xbf, const u16* __restrict__ abf,
    const int* __restrict__ starts, u16* __restrict__ u) {
  const int l = threadIdx.x & 63;
  const int w = threadIdx.x >> 6;
  const int mbase = blockIdx.x * 16 + w * 4;
  const int b = mbase >> 11;  // /2048
  const int seg = seg_of_batch(starts, b);
  const int use = seg > 0;
  int ad = seg - 1; ad = ad < 0 ? 0 : (ad > 2 ? 2 : ad);

  float acc[4][16];
#pragma unroll
  for (int row = 0; row < 4; ++row)
#pragma unroll
    for (int r = 0; r < 16; ++r) acc[row][r] = 0.f;

  if (use) {
    const u16* xr = xbf + (size_t)mbase * K_DIM + l * 8;
    const u16* ar = abf + (size_t)ad * (16 * K_DIM) + l * 8;
    for (int pass = 0; pass < 8; ++pass) {
      const int off = pass * 512;
      float xv[4][8];
#pragma unroll
      for (int row = 0; row < 4; ++row) {
        short8 xs = *(const short8*)(xr + (size_t)row * K_DIM + off);
#pragma unroll
        for (int j = 0; j < 8; ++j) xv[row][j] = bf2f((u16)xs[j]);
      }
#pragma unroll
      for (int r = 0; r < 16; ++r) {
        short8 av = *(const short8*)(ar + (size_t)r * K_DIM + off);
#pragma unroll
        for (int j = 0; j < 8; ++j) {
          float a = bf2f((u16)av[j]);
#pragma unroll
          for (int row = 0; row < 4; ++row) acc[row][r] += xv[row][j] * a;
        }
      }
    }
  }
#pragma unroll
  for (int row = 0; row < 4; ++row) {
    float myval = 0.f;
#pragma unroll
    for (int r = 0; r < 16; ++r) {
      float v = acc[row][r];
      v += __shfl_xor(v, 32);
      v += __shfl_xor(v, 16);
      v += __shfl_xor(v, 8);
      v += __shfl_xor(v, 4);
      v += __shfl_xor(v, 2);
      v += __shfl_xor(v, 1);
      if (l == r) myval = v;  // lane r keeps u[m][r]
    }
    if (l < 32) u[(size_t)(mbase + row) * 32 + l] = (l < 16) ? f2bf(myval) : (u16)0;
  }
}

// ---------------- main NT-GEMM, 256x256 tile, 1-barrier windows ----------------
// 512 threads = 8 waves (2 M-waves x 4 N-waves); each wave owns 128x64 output.
// Consumption: W1..W4 = tile 2s (buf0) quadrants (0,0),(0,1),(1,1),(1,0);
//              W5..W8 = tile 2s+1 (buf1) same order.
// Reads (for NEXT window's MFMA, issued post-MFMA): W8:A0b0+B0b0, W1:B1b0,
// W2:A1b0, W3:-, W4:A0b1+B0b1, W5:B1b1, W6:A1b1, W7:-.
// Stages: W1:A0b1+B1b1(t1), W2:B0b1(t1), W3:A1b1(t1), W4:A0b0(t2),
// W5:B1b0(t2), W6:B0b0(t2), W7:A1b0(t2), W8:-.
// Counted vmcnts (publication = vmcnt + next barrier; queue-simulated):
// end-W1 VMCNT(4) [publishes W7-prev A1b0 for W2-reads], end-W3 VMCNT(2)
// [publishes W1,W2 stages for W4/W5-reads], end-W5 VMCNT(4) [publishes W3 for
// W6-reads], end-W7 VMCNT(2) [publishes W4,W5,W6 for W8/W1'-reads].
// Write-hazards: every region re-staged >=2 windows after its last read
// (reads in Wr complete before MFMA(Wr+1) < bar1(Wr+2) <= stage window).
// T2 swizzle: physical 16B slot = logical slot ^ (row&7), applied on the
// gload16 *global source* (LDS dest linear, rule #21) and on ds_read.

#define STAGE_A(buf, ih, kt) do { \
  gload16(aSrc + (size_t)((ih)*64) * K2 + (size_t)(kt)*128, \
          &As[buf][((ih)*64) * BK] + w * 512); \
  gload16(aSrc + (size_t)((ih)*64 + 128) * K2 + (size_t)(kt)*128, \
          &As[buf][((ih)*64 + 128) * BK] + w * 512); \
} while (0)
#define STAGE_B(buf, jh, kt) do { \
  gload16(bSrc + (size_t)((jh)*32) * K2 + (size_t)(kt)*128, \
          &Bs[buf][((jh)*32 + (w >> 2)*64) * BK] + (w & 3) * 512); \
  gload16(bSrc + (size_t)((jh)*32 + 128) * K2 + (size_t)(kt)*128, \
          &Bs[buf][((jh)*32 + (w >> 2)*64 + 128) * BK] + (w & 3) * 512); \
} while (0)

#define READ_A(dst, buf, ih) do { \
  _Pragma("unroll") \
  for (int i2 = 0; i2 < 4; ++i2) { \
    const u16* ar = &As[buf][(wr*128 + (ih)*64 + i2*16 + fm) * BK]; \
    dst[i2][0] = *(const short8*)(ar + c0); \
    dst[i2][1] = *(const short8*)(ar + c1); \
  } \
} while (0)
#define READ_B(dst, buf, jh) do { \
  _Pragma("unroll") \
  for (int j2 = 0; j2 < 2; ++j2) { \
    const u16* br = &Bs[buf][(wc*64 + (jh)*32 + j2*16 + fm) * BK]; \
    dst[j2][0] = *(const short8*)(br + c0); \
    dst[j2][1] = *(const short8*)(br + c1); \
  } \
} while (0)

#define MFMA16(ih, jh, A, B) do { \
  __builtin_amdgcn_s_setprio(1); \
  _Pragma("unroll") \
  for (int i2 = 0; i2 < 4; ++i2) \
  _Pragma("unroll") \
  for (int j2 = 0; j2 < 2; ++j2) { \
    acc[(ih)*4 + i2][(jh)*2 + j2] = __builtin_amdgcn_mfma_f32_16x16x32_bf16( \
        A[i2][0], B[j2][0], acc[(ih)*4 + i2][(jh)*2 + j2], 0, 0, 0); \
    acc[(ih)*4 + i2][(jh)*2 + j2] = __builtin_amdgcn_mfma_f32_16x16x32_bf16( \
        A[i2][1], B[j2][1], acc[(ih)*4 + i2][(jh)*2 + j2], 0, 0, 0); \
  } \
  __builtin_amdgcn_s_setprio(0); \
} while (0)

__global__ __launch_bounds__(512, 2) void gemm8_kernel(
    const u16* __restrict__ xbf, const u16* __restrict__ wbf,
    const float* __restrict__ bias, const u16* __restrict__ ubuf,
    const u16* __restrict__ bwpad, const int* __restrict__ starts,
    float* __restrict__ out) {
  __shared__ u16 As[2][BM * BK];  // 64 KB
  __shared__ u16 Bs[2][BN * BK];  // 64 KB

  const int tid = threadIdx.x;
  const int l = tid & 63;
  const int w = tid >> 6;

  // T1: bijective XCD swizzle (1024 blocks, 1024 % 8 == 0)
  const int bid = blockIdx.x;
  const int nb = (bid & 7) * 128 + (bid >> 3);
  const int m0 = (nb >> 4) << 8;  // 64 M-tiles
  const int n0 = (nb & 15) << 8;  // 16 N-tiles

  const int b = m0 >> 11;  // block fully inside one batch sample (2048 rows)
  const int seg = seg_of_batch(starts, b);
  int ad = seg - 1; ad = ad < 0 ? 0 : (ad > 2 ? 2 : ad);
  // (no-LoRA blocks: u rows are zero, so the LoRA tile contributes nothing)

  // ---- staging constants: wave w covers 8 consecutive rows per gload16 ----
  const int lrow = l >> 3;                  // row within 8-row chunk
  const int swzslot = (l & 7) ^ lrow;       // pre-swizzled global 16B slot
  const char* aSrc = (const char*)xbf +
      (size_t)(m0 + 8 * w + lrow) * K2 + swzslot * 16;
  const char* bSrc = (const char*)wbf +
      (size_t)(n0 + (w >> 2) * 64 + (w & 3) * 8 + lrow) * K2 + swzslot * 16;

  // ---- fragment-read constants ----
  const int fm = l & 15;
  const int q = l >> 4;
  const int wr = w >> 2;  // 0..1
  const int wc = w & 3;   // 0..3
  const int c0 = ((q ^ (fm & 7)) * 8);        // u16 offset, k-step 0 (swizzled)
  const int c1 = (((q + 4) ^ (fm & 7)) * 8);  // u16 offset, k-step 1

  f32x4 acc[8][4];
  const f32x4 z4 = {0.f, 0.f, 0.f, 0.f};
#pragma unroll
  for (int i = 0; i < 8; ++i)
#pragma unroll
    for (int j = 0; j < 4; ++j) acc[i][j] = z4;

  // persistent register fragments
  short8 aF0r[4][2];  // A ih=0 half of current tile
  short8 aF1r[4][2];  // A ih=1 half
  short8 bF0r[2][2];  // B jh=0 half
  short8 bF1r[2][2];  // B jh=1 half

  // ---- prologue: all 4 regions of tile0 (buf0); drain once (cold start);
  // then issue reads for W1's MFMA.
  STAGE_A(0, 0, 0); STAGE_B(0, 0, 0); STAGE_B(0, 1, 0); STAGE_A(0, 1, 0);
  VMCNT(0);
  BAR();
  READ_A(aF0r, 0, 0);
  READ_B(bF0r, 0, 0);

  // ---- main loop: 32 iterations x 2 K-tiles (K = 64 tiles) ----
  for (int s = 0; s < 32; ++s) {
    const int t1 = 2 * s + 1;
    const int t2 = 2 * s + 2;
    const bool more = (s < 31);

    // W1: MFMA (0,0) buf0
    BAR();
    MFMA16(0, 0, aF0r, bF0r);
    READ_B(bF1r, 0, 1);
    STAGE_A(1, 0, t1);
    STAGE_B(1, 1, t1);
    VMCNT(4);

    // W2: MFMA (0,1) buf0
    BAR();
    MFMA16(0, 1, aF0r, bF1r);
    READ_A(aF1r, 0, 1);
    STAGE_B(1, 0, t1);

    // W3: MFMA (1,1) buf0 — no reads
    BAR();
    MFMA16(1, 1, aF1r, bF1r);
    STAGE_A(1, 1, t1);
    VMCNT(2);

    // W4: MFMA (1,0) buf0; read next tile's A0+B0 (buf1)
    BAR();
    MFMA16(1, 0, aF1r, bF0r);
    READ_A(aF0r, 1, 0);
    READ_B(bF0r, 1, 0);
    if (more) STAGE_A(0, 0, t2);

    // W5: MFMA (0,0) buf1
    BAR();
    MFMA16(0, 0, aF0r, bF0r);
    READ_B(bF1r, 1, 1);
    if (more) STAGE_B(0, 1, t2);
    if (more) { VMCNT(4); } else { VMCNT(0); }

    // W6: MFMA (0,1) buf1
    BAR();
    MFMA16(0, 1, aF0r, bF1r);
    READ_A(aF1r, 1, 1);
    if (more) STAGE_B(0, 0, t2);

    // W7: MFMA (1,1) buf1 — no reads
    BAR();
    MFMA16(1, 1, aF1r, bF1r);
    if (more) STAGE_A(0, 1, t2);
    if (more) { VMCNT(2); } else { VMCNT(0); }

    // W8: MFMA (1,0) buf1; read next even tile's A0+B0 (buf0)
    BAR();
    MFMA16(1, 0, aF1r, bF0r);
    if (more) {
      READ_A(aF0r, 0, 0);
      READ_B(bF0r, 0, 0);
    }
  }

  // ---- LoRA K=32 tile: A = u[M][32], B = bwpad[ad][N][32]; into buf0 flat ----
  {
    u16* la = &As[0][0];  // [256][32] packed, 16KB
    u16* lb = &Bs[0][0];
    const int ls = l & 3;  // 16B slot within 64B row
    const int lr = l >> 2; // row within 16-row chunk
    const char* uSrc = (const char*)ubuf +
        (size_t)(m0 + 16 * w + lr) * 64 + ls * 16;
    const char* vSrc = (const char*)bwpad +
        ((size_t)ad * N_DIM + n0 + 16 * w + lr) * 64 + ls * 16;
    gload16(uSrc, la + (16 * w) * 32);
    gload16(uSrc + (size_t)128 * 64, la + (128 + 16 * w) * 32);
    gload16(vSrc, lb + (16 * w) * 32);
    gload16(vSrc + (size_t)128 * 64, lb + (128 + 16 * w) * 32);
    VMCNT(0);
    BAR();
    short8 aF[8], bF[4];
#pragma unroll
    for (int i = 0; i < 8; ++i)
      aF[i] = *(const short8*)(la + (wr * 128 + i * 16 + fm) * 32 + q * 8);
#pragma unroll
    for (int j = 0; j < 4; ++j)
      bF[j] = *(const short8*)(lb + (wc * 64 + j * 16 + fm) * 32 + q * 8);
#pragma unroll
    for (int i = 0; i < 8; ++i)
#pragma unroll
      for (int j = 0; j < 4; ++j)
        acc[i][j] = __builtin_amdgcn_mfma_f32_16x16x32_bf16(aF[i], bF[j],
                                                            acc[i][j], 0, 0, 0);
  }

  // ---- epilogue: C/D layout col=l&15, row=(l>>4)*4+reg ----
  float bv[4];
#pragma unroll
  for (int j = 0; j < 4; ++j) bv[j] = bias[n0 + wc * 64 + j * 16 + fm];
#pragma unroll
  for (int i = 0; i < 8; ++i) {
#pragma unroll
    for (int ii = 0; ii < 4; ++ii) {
      const int m = m0 + wr * 128 + i * 16 + q * 4 + ii;
      float* orow = out + (size_t)m * N_DIM + n0 + wc * 64 + fm;
#pragma unroll
      for (int j = 0; j < 4; ++j) orow[j * 16] = acc[i][j][ii] + bv[j];
    }
  }
}

// ---------------- fp32 fallback (only if ws_size < fast-path need) ----------------
__global__ __launch_bounds__(256) void u_f32_kernel(
    const float* __restrict__ x, const float* __restrict__ lA,
    const int* __restrict__ starts, float* __restrict__ u) {
  const int l = threadIdx.x & 63;
  const int w = threadIdx.x >> 6;
  const int m = blockIdx.x * 4 + w;
  const int b = m >> 11;
  const int seg = seg_of_batch(starts, b);
  const int use = seg > 0;
  int ad = seg - 1; ad = ad < 0 ? 0 : (ad > 2 ? 2 : ad);
  float acc[16];
#pragma unroll
  for (int r = 0; r < 16; ++r) acc[r] = 0.f;
  if (use) {
    const float* xr = x + (size_t)m * K_DIM + l * 4;
    const float* ar = lA + (size_t)ad * (16 * K_DIM) + l * 4;
    for (int pass = 0; pass < 16; ++pass) {
      const int off = pass * 256;
      f32x4 xv = *(const f32x4*)(xr + off);
#pragma unroll
      for (int r = 0; r < 16; ++r) {
        f32x4 av = *(const f32x4*)(ar + (size_t)r * K_DIM + off);
        acc[r] += xv.x * av.x + xv.y * av.y + xv.z * av.z + xv.w * av.w;
      }
    }
  }
  float myval = 0.f;
#pragma unroll
  for (int r = 0; r < 16; ++r) {
    float v = acc[r];
    v += __shfl_xor(v, 32);
    v += __shfl_xor(v, 16);
    v += __shfl_xor(v, 8);
    v += __shfl_xor(v, 4);
    v += __shfl_xor(v, 2);
    v += __shfl_xor(v, 1);
    if (l == r) myval = v;
  }
  if (l < 16) u[(size_t)m * 16 + l] = myval;
}

__global__ __launch_bounds__(256) void gemm_f32_fallback(
    const float* __restrict__ x, const float* __restrict__ wgt,
    const float* __restrict__ bias, const float* __restrict__ lB,
    const float* __restrict__ u, const int* __restrict__ starts,
    float* __restrict__ out) {
  __shared__ float xs[4096];
  const int m = blockIdx.y;
  const int n0 = blockIdx.x * 256;
  const int t = threadIdx.x;
  const f32x4* xr4 = (const f32x4*)(x + (size_t)m * K_DIM);
  f32x4* xs4 = (f32x4*)xs;
  for (int i = t; i < 1024; i += 256) xs4[i] = xr4[i];
  __syncthreads();
  const int b = m >> 11;
  const int seg = seg_of_batch(starts, b);
  const int use = seg > 0;
  int ad = seg - 1; ad = ad < 0 ? 0 : (ad > 2 ? 2 : ad);
  const int n = n0 + t;
  const f32x4* wr = (const f32x4*)(wgt + (size_t)n * K_DIM);
  float acc = 0.f;
  for (int kk = 0; kk < 1024; ++kk) {
    f32x4 wv = wr[kk];
    f32x4 xv = xs4[kk];
    acc += xv.x * wv.x + xv.y * wv.y + xv.z * wv.z + xv.w * wv.w;
  }
  acc += bias[n];
  if (use) {
    const float* Bn = lB + ((size_t)ad * N_DIM + n) * 16;
    const float* um = u + (size_t)m * 16;
    float lo = 0.f;
#pragma unroll
    for (int r = 0; r < 16; ++r) lo += um[r] * Bn[r];
    acc += lo;
  }
  out[(size_t)m * N_DIM + n] = acc;
}

extern "C" void kernel_launch(void* const* d_in, const int* in_sizes, int n_in,
                              void* d_out, int out_size, void* d_ws, size_t ws_size,
                              hipStream_t stream) {
  const float* x    = (const float*)d_in[0];
  const float* wgt  = (const float*)d_in[1];
  const float* bias = (const float*)d_in[2];
  const float* lA   = (const float*)d_in[3];
  const float* lB   = (const float*)d_in[4];
  const int* starts = (const int*)d_in[5];
  float* out = (float*)d_out;

  const size_t XBF_OFF = 0;                      // 134217728 B
  const size_t WBF_OFF = 134217728;              //  33554432 B
  const size_t ABF_OFF = 167772160;              //    393216 B
  const size_t BW_OFF  = 168165376;              //    786432 B
  const size_t U_OFF   = 168951808;              //   1048576 B
  const size_t WS_NEEDED = 170000384;

  if (ws_size >= WS_NEEDED) {
    u16* xbf = (u16*)((char*)d_ws + XBF_OFF);
    u16* wbf = (u16*)((char*)d_ws + WBF_OFF);
    u16* abf = (u16*)((char*)d_ws + ABF_OFF);
    u16* bw  = (u16*)((char*)d_ws + BW_OFF);
    u16* u   = (u16*)((char*)d_ws + U_OFF);
    prep_kernel<<<8192, 256, 0, stream>>>(x, wgt, lA, lB, xbf, wbf, abf, bw);
    ucompute_kernel<<<1024, 256, 0, stream>>>(xbf, abf, starts, u);
    gemm8_kernel<<<1024, 512, 0, stream>>>(xbf, wbf, bias, u, bw, starts, out);
  } else {
    // fp32 fallback: needs only 1 MB of ws for u
    float* uf = (float*)d_ws;
    u_f32_kernel<<<4096, 256, 0, stream>>>(x, lA, starts, uf);
    gemm_f32_fallback<<<dim3(16, 16384), 256, 0, stream>>>(x, wgt, bias, lB, uf, starts, out);
  }
}